// Round 9
// baseline (383.067 us; speedup 1.0000x reference)
//
#include <hip/hip_runtime.h>

#define B_ 8
#define H_ 128
#define W_ 256
#define C_ 64
#define F_ 64
#define LOG2E 1.44269504f

typedef __attribute__((ext_vector_type(8))) short short8;
typedef __attribute__((ext_vector_type(8))) _Float16 half8;
typedef __attribute__((ext_vector_type(4))) float f32x4;

__device__ __forceinline__ unsigned short f2h(float x) {
    _Float16 h = (_Float16)x;
    return __builtin_bit_cast(unsigned short, h);
}

__device__ __forceinline__ f32x4 mfma16(short8 a, short8 b, f32x4 c) {
    return __builtin_amdgcn_mfma_f32_16x16x32_f16(
        __builtin_bit_cast(half8, a), __builtin_bit_cast(half8, b), c, 0, 0, 0);
}

// ---------------------------------------------------------------------------
// Pre-kernel: transpose+convert weights to fp16  Wt[tap(9)][f(192)][c(64)].
// ---------------------------------------------------------------------------
__global__ void wprep_kernel(const float* __restrict__ Wq,
                             const float* __restrict__ Wk,
                             const float* __restrict__ Wv,
                             unsigned short* __restrict__ Wt)
{
    int e = blockIdx.x * 256 + threadIdx.x;           // < 110592
    int c   = e & 63;
    int f   = (e >> 6) % 192;
    int tap = e / 12288;
    const float* src = (f < 64) ? Wq : (f < 128) ? Wk : Wv;
    int ff = f & 63;
    float v = src[(long)tap * 4096 + c * 64 + ff];    // W[tap][c][F]
    Wt[e] = f2h(v);
}

// ---------------------------------------------------------------------------
// Fused q/k/v dilated 3x3 conv via fp16 MFMA, T14 async-staged.
// Grid: 1024 bh x 2 f-half x 2 w-half = 4096. 256 thr = 4 waves x 32 w-rows.
// Phase (kh,cc): ds_write(prev-loaded regs); barrier; issue next loads;
// compute (36 MFMA/wave); barrier.  LDS 30 KB. Q scaled by log2e.
// ---------------------------------------------------------------------------
#define XST 36   // Xs row stride in shorts (72 B)
#define WST 36   // Wls row stride

__global__ __launch_bounds__(256, 3) void conv_mfma(
    const float* __restrict__ X, const unsigned short* __restrict__ Wt,
    const float* __restrict__ bq, const float* __restrict__ bk,
    const float* __restrict__ bv,
    unsigned short* __restrict__ Qg, unsigned short* __restrict__ Kg,
    unsigned short* __restrict__ Vtg)
{
    __shared__ __align__(16) unsigned short Xs[132 * XST];   // [w-halo 132][c 32]
    __shared__ __align__(16) unsigned short Wls[288 * WST];  // [kw*96+f][c 32]

    const int tid  = threadIdx.x;
    const int wv   = tid >> 6;
    const int lane = tid & 63;
    const int l15  = lane & 15;
    const int g    = lane >> 4;
    const int bx   = blockIdx.x;
    const int bh   = bx >> 2;
    const int half = (bx >> 1) & 1;
    const int qh   = bx & 1;
    const int b    = bh >> 7;
    const int h    = bh & 127;

    // valid kh list (block-uniform)
    int khl[3]; int nkh = 0;
    #pragma unroll
    for (int kh = 0; kh < 3; ++kh) {
        const int ih = h + 2 * (kh - 1);
        if ((unsigned)ih < (unsigned)H_) khl[nkh++] = kh;
    }
    const int nph = nkh * 2;

    float4 xv[5];     // X stage regs (1056 float4 / 256 thr)
    uint4  wv4[5];    // W stage regs (1152 uint4 / 256 thr)

    #define CONV_LOAD(p)                                                        \
    {                                                                           \
        const int kh_ = khl[(p) >> 1], c0_ = ((p) & 1) * 32;                    \
        const int ih_ = h + 2 * (kh_ - 1);                                      \
        const float* Xr_ = X + ((long)(b * H_ + ih_) * W_) * C_;                \
        _Pragma("unroll")                                                       \
        for (int it = 0; it < 4; ++it) {                                        \
            const int e = tid + it * 256;                                       \
            const int row = e >> 3, c4 = e & 7;                                 \
            const int w_in = qh * 128 - 2 + row;                                \
            xv[it] = ((unsigned)w_in < (unsigned)W_)                            \
                ? *(const float4*)(Xr_ + (long)w_in * 64 + c0_ + c4 * 4)        \
                : make_float4(0.f, 0.f, 0.f, 0.f);                              \
        }                                                                       \
        if (tid < 32) {                                                         \
            const int e = 1024 + tid;                                           \
            const int row = e >> 3, c4 = e & 7;                                 \
            const int w_in = qh * 128 - 2 + row;                                \
            xv[4] = ((unsigned)w_in < (unsigned)W_)                             \
                ? *(const float4*)(Xr_ + (long)w_in * 64 + c0_ + c4 * 4)        \
                : make_float4(0.f, 0.f, 0.f, 0.f);                              \
        }                                                                       \
        _Pragma("unroll")                                                       \
        for (int it = 0; it < 4; ++it) {                                        \
            const int e = tid + it * 256;                                       \
            const int c8 = e & 3, f = (e >> 2) % 96, kw = e / 384;              \
            wv4[it] = *(const uint4*)(Wt +                                      \
                (((long)(kh_ * 3 + kw) * 192 + half * 96 + f) * 64 + c0_ + c8 * 8)); \
        }                                                                       \
        if (tid < 128) {                                                        \
            const int e = 1024 + tid;                                           \
            const int c8 = e & 3, f = (e >> 2) % 96, kw = e / 384;              \
            wv4[4] = *(const uint4*)(Wt +                                       \
                (((long)(kh_ * 3 + kw) * 192 + half * 96 + f) * 64 + c0_ + c8 * 8)); \
        }                                                                       \
    }

    #define CONV_WRITE()                                                        \
    {                                                                           \
        _Pragma("unroll")                                                       \
        for (int it = 0; it < 4; ++it) {                                        \
            const int e = tid + it * 256;                                       \
            const int row = e >> 3, c4 = e & 7;                                 \
            uint2 p_;                                                           \
            p_.x = (unsigned)f2h(xv[it].x) | ((unsigned)f2h(xv[it].y) << 16);   \
            p_.y = (unsigned)f2h(xv[it].z) | ((unsigned)f2h(xv[it].w) << 16);   \
            *(uint2*)(Xs + row * XST + c4 * 4) = p_;                            \
        }                                                                       \
        if (tid < 32) {                                                         \
            const int e = 1024 + tid;                                           \
            const int row = e >> 3, c4 = e & 7;                                 \
            uint2 p_;                                                           \
            p_.x = (unsigned)f2h(xv[4].x) | ((unsigned)f2h(xv[4].y) << 16);     \
            p_.y = (unsigned)f2h(xv[4].z) | ((unsigned)f2h(xv[4].w) << 16);     \
            *(uint2*)(Xs + row * XST + c4 * 4) = p_;                            \
        }                                                                       \
        _Pragma("unroll")                                                       \
        for (int it = 0; it < 4; ++it) {                                        \
            const int e = tid + it * 256;                                       \
            const int c8 = e & 3, f = (e >> 2) % 96, kw = e / 384;              \
            *(uint4*)(Wls + (kw * 96 + f) * WST + c8 * 8) = wv4[it];            \
        }                                                                       \
        if (tid < 128) {                                                        \
            const int e = 1024 + tid;                                           \
            const int c8 = e & 3, f = (e >> 2) % 96, kw = e / 384;              \
            *(uint4*)(Wls + (kw * 96 + f) * WST + c8 * 8) = wv4[4];             \
        }                                                                       \
    }

    f32x4 acc[2][6];
    #pragma unroll
    for (int mt = 0; mt < 2; ++mt)
        #pragma unroll
        for (int nt = 0; nt < 6; ++nt)
            acc[mt][nt] = (f32x4){0.f, 0.f, 0.f, 0.f};

    CONV_LOAD(0);

    for (int p = 0; p < nph; ++p) {
        CONV_WRITE();
        __syncthreads();                 // staged data visible
        if (p + 1 < nph) CONV_LOAD(p + 1);   // issue next loads; land during compute

        #pragma unroll
        for (int kw = 0; kw < 3; ++kw) {
            short8 bfrag[6];
            #pragma unroll
            for (int nt = 0; nt < 6; ++nt)
                bfrag[nt] = *(const short8*)(Wls +
                    (kw * 96 + nt * 16 + l15) * WST + g * 8);
            #pragma unroll
            for (int mt = 0; mt < 2; ++mt) {
                const int row = wv * 32 + mt * 16 + l15 + 2 * kw;
                short8 a = *(const short8*)(Xs + row * XST + g * 8);
                #pragma unroll
                for (int nt = 0; nt < 6; ++nt)
                    acc[mt][nt] = mfma16(a, bfrag[nt], acc[mt][nt]);
            }
        }
        __syncthreads();                 // reads done before next write
    }

    // ---- epilogue: bias (+ log2e scale on Q) + store fp16 ----
    float bias[6];
    #pragma unroll
    for (int nt = 0; nt < 6; ++nt) {
        const int fp = half * 96 + nt * 16 + l15;
        bias[nt] = (fp < 64) ? bq[fp] : (fp < 128) ? bk[fp - 64] : bv[fp - 128];
    }
    #pragma unroll
    for (int mt = 0; mt < 2; ++mt) {
        const int wrow = qh * 128 + wv * 32 + mt * 16 + 4 * g;
        #pragma unroll
        for (int nt = 0; nt < 6; ++nt) {
            const int fp = half * 96 + nt * 16 + l15;
            if (fp < 64) {            // Q: scale by log2e
                #pragma unroll
                for (int r = 0; r < 4; ++r)
                    Qg[((long)bh * 256 + wrow + r) * 64 + fp] =
                        f2h((acc[mt][nt][r] + bias[nt]) * LOG2E);
            } else if (fp < 128) {    // K
                const int f = fp - 64;
                #pragma unroll
                for (int r = 0; r < 4; ++r)
                    Kg[((long)bh * 256 + wrow + r) * 64 + f] =
                        f2h(acc[mt][nt][r] + bias[nt]);
            } else {                  // V transposed: [bh][f][w]
                const int f = fp - 128;
                uint2 p;
                p.x = (unsigned)f2h(acc[mt][nt][0] + bias[nt]) |
                      ((unsigned)f2h(acc[mt][nt][1] + bias[nt]) << 16);
                p.y = (unsigned)f2h(acc[mt][nt][2] + bias[nt]) |
                      ((unsigned)f2h(acc[mt][nt][3] + bias[nt]) << 16);
                *(uint2*)(Vtg + ((long)bh * 64 + f) * 256 + wrow) = p;
            }
        }
    }
}

// ---------------------------------------------------------------------------
// Flash attention via fp16 MFMA, T14 async-staged. Grid 2048 = bh x q-half.
// 256 thr = 4 waves x 32 q-rows. K/V single LDS buffer + reg-staged next
// tile. Softmax in exp2 space (Q pre-scaled); defer-max THR=11.5.
// ---------------------------------------------------------------------------
#define KST 72
#define PST 72

__global__ __launch_bounds__(256, 2) void attn_mfma(
    const unsigned short* __restrict__ Qg, const unsigned short* __restrict__ Kg,
    const unsigned short* __restrict__ Vtg, float* __restrict__ Out)
{
    __shared__ __align__(16) unsigned short Ks[64 * KST];       // 9.2 KB
    __shared__ __align__(16) unsigned short Vts[64 * KST];      // 9.2 KB
    __shared__ __align__(16) unsigned short Ps[4][32 * PST];    // 18.4 KB

    const int tid  = threadIdx.x;
    const int wv   = tid >> 6;
    const int lane = tid & 63;
    const int l15  = lane & 15;
    const int g    = lane >> 4;
    const int bx   = blockIdx.x;
    const long bh  = bx >> 1;
    const int qh   = bx & 1;

    // ---- Q fragments direct from global ----
    short8 qf[2][2];
    #pragma unroll
    for (int mt = 0; mt < 2; ++mt)
        #pragma unroll
        for (int kt = 0; kt < 2; ++kt)
            qf[mt][kt] = *(const short8*)(Qg +
                (bh * 256 + qh * 128 + wv * 32 + mt * 16 + l15) * 64 + (kt * 4 + g) * 8);

    const int srow = tid >> 2, sch = (tid & 3) * 16;
    uint4 kreg[2], vreg[2];

    #define ATTN_LOAD(t)                                                        \
    {                                                                           \
        const unsigned short* kp = Kg + (bh * 256 + (t) * 64 + srow) * 64 + sch;\
        const unsigned short* vp = Vtg + (bh * 64 + srow) * 256 + (t) * 64 + sch;\
        kreg[0] = *(const uint4*)(kp);                                          \
        kreg[1] = *(const uint4*)(kp + 8);                                      \
        vreg[0] = *(const uint4*)(vp);                                          \
        vreg[1] = *(const uint4*)(vp + 8);                                      \
    }
    #define ATTN_WRITE()                                                        \
    {                                                                           \
        *(uint4*)(Ks + srow * KST + sch)      = kreg[0];                        \
        *(uint4*)(Ks + srow * KST + sch + 8)  = kreg[1];                        \
        *(uint4*)(Vts + srow * KST + sch)     = vreg[0];                        \
        *(uint4*)(Vts + srow * KST + sch + 8) = vreg[1];                        \
    }

    ATTN_LOAD(0);
    ATTN_WRITE();

    f32x4 po[2][4], lacc[2];
    float mrun[2][4];
    #pragma unroll
    for (int mt = 0; mt < 2; ++mt) {
        #pragma unroll
        for (int nt = 0; nt < 4; ++nt) po[mt][nt] = (f32x4){0.f,0.f,0.f,0.f};
        lacc[mt] = (f32x4){0.f,0.f,0.f,0.f};
        #pragma unroll
        for (int r = 0; r < 4; ++r) mrun[mt][r] = -3.0e38f;
    }

    short8 ones;
    #pragma unroll
    for (int i = 0; i < 8; ++i) ones[i] = (short)0x3C00;   // fp16 1.0

    unsigned short* Pw = &Ps[wv][0];

    for (int t = 0; t < 4; ++t) {
        __syncthreads();                  // staged tile visible
        if (t < 3) ATTN_LOAD(t + 1);      // issue next loads early

        // ---- QK^T: S[32 w][64 kv] per wave (exp2-scaled scores) ----
        f32x4 s[2][4];
        #pragma unroll
        for (int mt = 0; mt < 2; ++mt)
            #pragma unroll
            for (int nt = 0; nt < 4; ++nt) s[mt][nt] = (f32x4){0.f,0.f,0.f,0.f};
        #pragma unroll
        for (int kt = 0; kt < 2; ++kt)
            #pragma unroll
            for (int nt = 0; nt < 4; ++nt) {
                short8 kb = *(const short8*)(Ks +
                    (nt * 16 + l15) * KST + (kt * 4 + g) * 8);
                #pragma unroll
                for (int mt = 0; mt < 2; ++mt)
                    s[mt][nt] = mfma16(qf[mt][kt], kb, s[mt][nt]);
            }

        // ---- online softmax (exp2, defer-max THR=11.5) ----
        #pragma unroll
        for (int mt = 0; mt < 2; ++mt) {
            float tm[4];
            #pragma unroll
            for (int r = 0; r < 4; ++r) {
                float a0 = fmaxf(s[mt][0][r], s[mt][1][r]);
                float a1 = fmaxf(s[mt][2][r], s[mt][3][r]);
                float t0 = fmaxf(a0, a1);
                t0 = fmaxf(t0, __shfl_xor(t0, 1));
                t0 = fmaxf(t0, __shfl_xor(t0, 2));
                t0 = fmaxf(t0, __shfl_xor(t0, 4));
                t0 = fmaxf(t0, __shfl_xor(t0, 8));
                tm[r] = t0;
            }
            float worst = tm[0] - mrun[mt][0];
            #pragma unroll
            for (int r = 1; r < 4; ++r) worst = fmaxf(worst, tm[r] - mrun[mt][r]);
            if (__all(worst <= 11.5f)) {      // defer: keep old max
                #pragma unroll
                for (int r = 0; r < 4; ++r) {
                    const float mo = mrun[mt][r];
                    const int wrow = mt * 16 + 4 * g + r;
                    #pragma unroll
                    for (int nt = 0; nt < 4; ++nt)
                        Pw[wrow * PST + nt * 16 + l15] = f2h(exp2f(s[mt][nt][r] - mo));
                }
            } else {
                #pragma unroll
                for (int r = 0; r < 4; ++r) {
                    const float mo = mrun[mt][r];
                    const float mn = fmaxf(mo, tm[r]);
                    const float al = exp2f(mo - mn);
                    mrun[mt][r] = mn;
                    lacc[mt][r] *= al;
                    #pragma unroll
                    for (int nf = 0; nf < 4; ++nf) po[mt][nf][r] *= al;
                    const int wrow = mt * 16 + 4 * g + r;
                    #pragma unroll
                    for (int nt = 0; nt < 4; ++nt)
                        Pw[wrow * PST + nt * 16 + l15] = f2h(exp2f(s[mt][nt][r] - mn));
                }
            }
        }

        // ---- PV: O += P[32][64] x V[64][64]; l via ones-MFMA ----
        #pragma unroll
        for (int kt = 0; kt < 2; ++kt) {
            short8 vb[4];
            #pragma unroll
            for (int nf = 0; nf < 4; ++nf)
                vb[nf] = *(const short8*)(Vts +
                    (nf * 16 + l15) * KST + (kt * 4 + g) * 8);
            #pragma unroll
            for (int mt = 0; mt < 2; ++mt) {
                short8 pa = *(const short8*)(Pw +
                    (mt * 16 + l15) * PST + (kt * 4 + g) * 8);
                #pragma unroll
                for (int nf = 0; nf < 4; ++nf)
                    po[mt][nf] = mfma16(pa, vb[nf], po[mt][nf]);
                lacc[mt] = mfma16(pa, ones, lacc[mt]);
            }
        }

        __syncthreads();                  // all reads of Ks/Vts done
        if (t < 3) ATTN_WRITE();          // vmcnt long satisfied
    }

    // ---- epilogue ----
    #pragma unroll
    for (int mt = 0; mt < 2; ++mt) {
        #pragma unroll
        for (int r = 0; r < 4; ++r) {
            const float inv = 1.0f / lacc[mt][r];
            const long wrow = bh * 256 + qh * 128 + wv * 32 + mt * 16 + 4 * g + r;
            #pragma unroll
            for (int nf = 0; nf < 4; ++nf)
                Out[wrow * 64 + nf * 16 + l15] = po[mt][nf][r] * inv;
        }
    }
}

extern "C" void kernel_launch(void* const* d_in, const int* in_sizes, int n_in,
                              void* d_out, int out_size, void* d_ws, size_t ws_size,
                              hipStream_t stream) {
    const float* X  = (const float*)d_in[0];
    const float* Wq = (const float*)d_in[1];
    const float* bq = (const float*)d_in[2];
    const float* Wk = (const float*)d_in[3];
    const float* bk = (const float*)d_in[4];
    const float* Wv = (const float*)d_in[5];
    const float* bv = (const float*)d_in[6];
    float* out = (float*)d_out;

    const size_t NE = (size_t)B_ * H_ * W_ * F_;      // 16,777,216
    unsigned short* q  = (unsigned short*)d_ws;
    unsigned short* k  = q + NE;
    unsigned short* vt = k + NE;
    unsigned short* wt = vt + NE;                      // 110592 shorts

    wprep_kernel<<<432, 256, 0, stream>>>(Wq, Wk, Wv, wt);
    conv_mfma<<<B_ * H_ * 4, 256, 0, stream>>>(X, wt, bq, bk, bv, q, k, vt);
    attn_mfma<<<B_ * H_ * 2, 256, 0, stream>>>(q, k, vt, out);
}